// Round 2
// baseline (254.597 us; speedup 1.0000x reference)
//
#include <hip/hip_runtime.h>
#include <stdint.h>

// Workspace-resident parameters computed on-device by setup_kernel (the grid
// bounds depend on input VALUES, which we may only touch on the GPU).
struct Params {
  int a_max, b_max, c_max;
  uint32_t Dj, Dk;        // Dj = (2b+1)*(2c+1), Dk = (2c+1)
  uint64_t Mj, Mk;        // magic multipliers: q = (n*M)>>47, exact for n<2^24
};

__device__ __forceinline__ int iabs_(int x) { return x < 0 ? -x : x; }

// Bit-exact replica of the reference's numpy fp64 nmax(): no fp contraction,
// same op order: cross -> ln=sqrt(dot) -> d=|dot(dr, cr/ln)| -> floor((co+d)/vol*ln)
__device__ __forceinline__ int nmax_ref(double u0, double u1, double u2,
                                        double v0, double v1, double v2,
                                        double dr0, double dr1, double dr2,
                                        double co, double vol) {
#pragma clang fp contract(off)
  double x0 = u1 * v2 - u2 * v1;
  double x1 = u2 * v0 - u0 * v2;
  double x2 = u0 * v1 - u1 * v0;
  double ln = sqrt((x0 * x0 + x1 * x1) + x2 * x2);
  double d  = fabs((dr0 * (x0 / ln) + dr1 * (x1 / ln)) + dr2 * (x2 / ln));
  double f  = floor((co + d) / vol * ln);
  long long n = (long long)f;
  if (n > 100000) n = 100000;
  return (int)n;
}

__global__ void setup_kernel(const float* __restrict__ cell,
                             const float* __restrict__ cutoff,
                             const float* __restrict__ r1,
                             const float* __restrict__ r2,
                             Params* __restrict__ p, int N) {
#pragma clang fp contract(off)
  double a0 = cell[0], a1 = cell[1], a2 = cell[2];
  double b0 = cell[3], b1 = cell[4], b2 = cell[5];
  double c0 = cell[6], c1 = cell[7], c2 = cell[8];
  double dr0 = (double)r2[0] - (double)r1[0];
  double dr1 = (double)r2[1] - (double)r1[1];
  double dr2 = (double)r2[2] - (double)r1[2];
  double co  = (double)cutoff[0];

  double bc0 = b1 * c2 - b2 * c1;
  double bc1 = b2 * c0 - b0 * c2;
  double bc2 = b0 * c1 - b1 * c0;
  double vol = fabs((a0 * bc0 + a1 * bc1) + a2 * bc2);

  int am = nmax_ref(b0, b1, b2, c0, c1, c2, dr0, dr1, dr2, co, vol);
  int bm = nmax_ref(a0, a1, a2, c0, c1, c2, dr0, dr1, dr2, co, vol);
  int cm = nmax_ref(a0, a1, a2, b0, b1, b2, dr0, dr1, dr2, co, vol);

  // Safety net: the harness tells us N = out_size/7; make sure our triple's
  // product matches. If a 1-ulp divergence from numpy shifted a bound, search
  // +-1 perturbations (nearest-first) for the product that matches N.
  int fa = am, fb = bm, fc = cm;
  bool found = ((long long)(2 * am + 1) * (2 * bm + 1) * (2 * cm + 1) == (long long)N);
  for (int r = 1; r <= 3 && !found; ++r)
    for (int da = -1; da <= 1 && !found; ++da)
      for (int db = -1; db <= 1 && !found; ++db)
        for (int dc = -1; dc <= 1 && !found; ++dc) {
          if (iabs_(da) + iabs_(db) + iabs_(dc) != r) continue;
          long long A = am + da, B = bm + db, C = cm + dc;
          if (A < 0 || B < 0 || C < 0) continue;
          long long P = (2 * A + 1) * (2 * B + 1) * (2 * C + 1);
          if (P == (long long)N) { fa = (int)A; fb = (int)B; fc = (int)C; found = true; }
        }

  p->a_max = fa; p->b_max = fb; p->c_max = fc;
  uint32_t Dk = (uint32_t)(2 * fc + 1);
  uint32_t Dj = (uint32_t)(2 * fb + 1) * Dk;
  p->Dk = Dk; p->Dj = Dj;
  // round-up magic division: q = (n*M)>>47 exact for n < 2^24, D < 2^17
  p->Mj = ((1ULL << 47) / Dj) + 1;
  p->Mk = ((1ULL << 47) / Dk) + 1;
}

__global__ __launch_bounds__(256) void periodic_main(
    const float* __restrict__ cell, const float* __restrict__ cutoff,
    const float* __restrict__ r1, const float* __restrict__ r2,
    const Params* __restrict__ p, float* __restrict__ out, int N) {
  int n = blockIdx.x * 256 + threadIdx.x;
  if (n >= N) return;

  const int am = p->a_max, bm = p->b_max, cm = p->c_max;
  const uint32_t Dj = p->Dj, Dk = p->Dk;
  const uint64_t Mj = p->Mj, Mk = p->Mk;

  uint32_t un  = (uint32_t)n;
  uint32_t qi  = (uint32_t)(((uint64_t)un * Mj) >> 47);
  uint32_t rem = un - qi * Dj;
  uint32_t qj  = (uint32_t)(((uint64_t)rem * Mk) >> 47);
  uint32_t qk  = rem - qj * Dk;

  float fi = (float)((int)qi - am);
  float fj = (float)((int)qj - bm);
  float fk = (float)((int)qk - cm);

  // uniform scalar loads (L1-cached, wave-uniform)
  float ax = cell[0], ay = cell[1], az = cell[2];
  float bx = cell[3], by = cell[4], bz = cell[5];
  float cx = cell[6], cy = cell[7], cz = cell[8];
  float drx = r2[0] - r1[0], dry = r2[1] - r1[1], drz = r2[2] - r1[2];

  // disp = ijk @ cell in f32, XLA-style k-ascending fmuladd accumulation
  float vx = fmaf(fk, cx, fmaf(fj, bx, fi * ax)) + drx;
  float vy = fmaf(fk, cy, fmaf(fj, by, fi * ay)) + dry;
  float vz = fmaf(fk, cz, fmaf(fj, bz, fi * az)) + drz;

  float s  = fmaf(vz, vz, fmaf(vy, vy, vx * vx));
  float co = cutoff[0];
  bool  m  = s < co * co;

  float vxo = m ? vx : 0.f, vyo = m ? vy : 0.f, vzo = m ? vz : 0.f;
  float fio = m ? fi : 0.f, fjo = m ? fj : 0.f, fko = m ? fk : 0.f;

  size_t base = (size_t)3 * (size_t)n;
  size_t N3   = (size_t)3 * (size_t)N;
  // streaming stores: output is never re-read, skip L2 allocation
  __builtin_nontemporal_store(vxo, out + base + 0);
  __builtin_nontemporal_store(vyo, out + base + 1);
  __builtin_nontemporal_store(vzo, out + base + 2);
  __builtin_nontemporal_store(fio, out + N3 + base + 0);
  __builtin_nontemporal_store(fjo, out + N3 + base + 1);
  __builtin_nontemporal_store(fko, out + N3 + base + 2);
  __builtin_nontemporal_store(m ? 1.0f : 0.0f, out + 2 * N3 + (size_t)n);
}

extern "C" void kernel_launch(void* const* d_in, const int* in_sizes, int n_in,
                              void* d_out, int out_size, void* d_ws, size_t ws_size,
                              hipStream_t stream) {
  const float* cell   = (const float*)d_in[0];
  const float* cutoff = (const float*)d_in[1];
  const float* r1     = (const float*)d_in[2];
  const float* r2     = (const float*)d_in[3];
  float* out = (float*)d_out;

  int N = out_size / 7;
  Params* p = (Params*)d_ws;

  setup_kernel<<<1, 1, 0, stream>>>(cell, cutoff, r1, r2, p, N);
  int blocks = (N + 255) / 256;
  periodic_main<<<blocks, 256, 0, stream>>>(cell, cutoff, r1, r2, p, out, N);
}

// Round 3
// 236.348 us; speedup vs baseline: 1.0772x; 1.0772x over previous
//
#include <hip/hip_runtime.h>
#include <stdint.h>

// Workspace-resident parameters computed on-device by setup_kernel (the grid
// bounds depend on input VALUES, which we may only touch on the GPU).
struct Params {
  int a_max, b_max, c_max;
  uint32_t Dj, Dk;        // Dj = (2b+1)*(2c+1), Dk = (2c+1)
  uint64_t Mj, Mk;        // magic multipliers: q = (n*M)>>47, exact for n<2^24
};

__device__ __forceinline__ int iabs_(int x) { return x < 0 ? -x : x; }

// Bit-exact replica of the reference's numpy fp64 nmax(): no fp contraction,
// same op order: cross -> ln=sqrt(dot) -> d=|dot(dr, cr/ln)| -> floor((co+d)/vol*ln)
__device__ __forceinline__ int nmax_ref(double u0, double u1, double u2,
                                        double v0, double v1, double v2,
                                        double dr0, double dr1, double dr2,
                                        double co, double vol) {
#pragma clang fp contract(off)
  double x0 = u1 * v2 - u2 * v1;
  double x1 = u2 * v0 - u0 * v2;
  double x2 = u0 * v1 - u1 * v0;
  double ln = sqrt((x0 * x0 + x1 * x1) + x2 * x2);
  double d  = fabs((dr0 * (x0 / ln) + dr1 * (x1 / ln)) + dr2 * (x2 / ln));
  double f  = floor((co + d) / vol * ln);
  long long n = (long long)f;
  if (n > 100000) n = 100000;
  return (int)n;
}

__global__ void setup_kernel(const float* __restrict__ cell,
                             const float* __restrict__ cutoff,
                             const float* __restrict__ r1,
                             const float* __restrict__ r2,
                             Params* __restrict__ p, int N) {
#pragma clang fp contract(off)
  double a0 = cell[0], a1 = cell[1], a2 = cell[2];
  double b0 = cell[3], b1 = cell[4], b2 = cell[5];
  double c0 = cell[6], c1 = cell[7], c2 = cell[8];
  double dr0 = (double)r2[0] - (double)r1[0];
  double dr1 = (double)r2[1] - (double)r1[1];
  double dr2 = (double)r2[2] - (double)r1[2];
  double co  = (double)cutoff[0];

  double bc0 = b1 * c2 - b2 * c1;
  double bc1 = b2 * c0 - b0 * c2;
  double bc2 = b0 * c1 - b1 * c0;
  double vol = fabs((a0 * bc0 + a1 * bc1) + a2 * bc2);

  int am = nmax_ref(b0, b1, b2, c0, c1, c2, dr0, dr1, dr2, co, vol);
  int bm = nmax_ref(a0, a1, a2, c0, c1, c2, dr0, dr1, dr2, co, vol);
  int cm = nmax_ref(a0, a1, a2, b0, b1, b2, dr0, dr1, dr2, co, vol);

  // Safety net: the harness tells us N = out_size/7; make sure our triple's
  // product matches. If a 1-ulp divergence from numpy shifted a bound, search
  // +-1 perturbations (nearest-first) for the product that matches N.
  int fa = am, fb = bm, fc = cm;
  bool found = ((long long)(2 * am + 1) * (2 * bm + 1) * (2 * cm + 1) == (long long)N);
  for (int r = 1; r <= 3 && !found; ++r)
    for (int da = -1; da <= 1 && !found; ++da)
      for (int db = -1; db <= 1 && !found; ++db)
        for (int dc = -1; dc <= 1 && !found; ++dc) {
          if (iabs_(da) + iabs_(db) + iabs_(dc) != r) continue;
          long long A = am + da, B = bm + db, C = cm + dc;
          if (A < 0 || B < 0 || C < 0) continue;
          long long P = (2 * A + 1) * (2 * B + 1) * (2 * C + 1);
          if (P == (long long)N) { fa = (int)A; fb = (int)B; fc = (int)C; found = true; }
        }

  p->a_max = fa; p->b_max = fb; p->c_max = fc;
  uint32_t Dk = (uint32_t)(2 * fc + 1);
  uint32_t Dj = (uint32_t)(2 * fb + 1) * Dk;
  p->Dk = Dk; p->Dj = Dj;
  // round-up magic division: q = (n*M)>>47 exact for n < 2^24, D < 2^17
  p->Mj = ((1ULL << 47) / Dj) + 1;
  p->Mk = ((1ULL << 47) / Dk) + 1;
}

// One block = 256 consecutive lattice points. Compute into LDS, then do
// perfectly-coalesced cooperative dword copies to the three output regions
// (lane i -> element i: 1 KB contiguous per wave store instruction). This
// replaces the round-2 stride-12B scalar nt stores that caused partial-line
// HBM writes (~3x write-BW loss), and sidesteps the 3N%4==3 misalignment of
// the idx region.
__global__ __launch_bounds__(256) void periodic_main(
    const float* __restrict__ cell, const float* __restrict__ cutoff,
    const float* __restrict__ r1, const float* __restrict__ r2,
    const Params* __restrict__ p, float* __restrict__ out, int N) {
  __shared__ float s_vec[3 * 256];
  __shared__ float s_idx[3 * 256];
  __shared__ float s_msk[256];

  const int tid = threadIdx.x;
  const int n0  = blockIdx.x << 8;
  const int n   = n0 + tid;

  const int am = p->a_max, bm = p->b_max, cm = p->c_max;
  const uint32_t Dj = p->Dj, Dk = p->Dk;
  const uint64_t Mj = p->Mj, Mk = p->Mk;

  // magic-div decomposition n -> (i,j,k); exact for n < 2^24 (N ~ 8.1M)
  uint32_t un  = (uint32_t)n;
  uint32_t qi  = (uint32_t)(((uint64_t)un * Mj) >> 47);
  uint32_t rem = un - qi * Dj;
  uint32_t qj  = (uint32_t)(((uint64_t)rem * Mk) >> 47);
  uint32_t qk  = rem - qj * Dk;

  float fi = (float)((int)qi - am);
  float fj = (float)((int)qj - bm);
  float fk = (float)((int)qk - cm);

  // wave-uniform scalar loads (L1-cached)
  float ax = cell[0], ay = cell[1], az = cell[2];
  float bx = cell[3], by = cell[4], bz = cell[5];
  float cx = cell[6], cy = cell[7], cz = cell[8];
  float drx = r2[0] - r1[0], dry = r2[1] - r1[1], drz = r2[2] - r1[2];

  // disp = ijk @ cell in f32, XLA-style k-ascending fmuladd accumulation
  float vx = fmaf(fk, cx, fmaf(fj, bx, fi * ax)) + drx;
  float vy = fmaf(fk, cy, fmaf(fj, by, fi * ay)) + dry;
  float vz = fmaf(fk, cz, fmaf(fj, bz, fi * az)) + drz;

  float s  = fmaf(vz, vz, fmaf(vy, vy, vx * vx));
  float co = cutoff[0];
  bool  m  = s < co * co;

  // LDS stage (stride-3 write = 2 lanes/bank = free)
  int b3 = 3 * tid;
  s_vec[b3 + 0] = m ? vx : 0.f;
  s_vec[b3 + 1] = m ? vy : 0.f;
  s_vec[b3 + 2] = m ? vz : 0.f;
  s_idx[b3 + 0] = m ? fi : 0.f;
  s_idx[b3 + 1] = m ? fj : 0.f;
  s_idx[b3 + 2] = m ? fk : 0.f;
  s_msk[tid]    = m ? 1.0f : 0.0f;
  __syncthreads();

  // cooperative coalesced copies (lane i -> dword i, contiguous)
  const int ptsLeft = N - n0;                    // >= 1 by grid construction
  const int pts     = ptsLeft < 256 ? ptsLeft : 256;
  const int c3      = 3 * pts;

  const size_t g0 = (size_t)3 * (size_t)n0;                    // vectors
  const size_t g1 = (size_t)3 * (size_t)N + (size_t)3 * n0;    // indices
  const size_t g2 = (size_t)6 * (size_t)N + (size_t)n0;        // mask

  for (int i = tid; i < c3; i += 256) out[g0 + i] = s_vec[i];
  for (int i = tid; i < c3; i += 256) out[g1 + i] = s_idx[i];
  if (tid < pts) out[g2 + tid] = s_msk[tid];
}

extern "C" void kernel_launch(void* const* d_in, const int* in_sizes, int n_in,
                              void* d_out, int out_size, void* d_ws, size_t ws_size,
                              hipStream_t stream) {
  const float* cell   = (const float*)d_in[0];
  const float* cutoff = (const float*)d_in[1];
  const float* r1     = (const float*)d_in[2];
  const float* r2     = (const float*)d_in[3];
  float* out = (float*)d_out;

  int N = out_size / 7;
  Params* p = (Params*)d_ws;

  setup_kernel<<<1, 1, 0, stream>>>(cell, cutoff, r1, r2, p, N);
  int blocks = (N + 255) / 256;
  periodic_main<<<blocks, 256, 0, stream>>>(cell, cutoff, r1, r2, p, out, N);
}

// Round 5
// 233.292 us; speedup vs baseline: 1.0913x; 1.0131x over previous
//
#include <hip/hip_runtime.h>
#include <stdint.h>

// Workspace-resident parameters computed on-device by setup_kernel (the grid
// bounds depend on input VALUES, which we may only touch on the GPU).
struct Params {
  int a_max, b_max, c_max;
  uint32_t Dj, Dk;        // Dj = (2b+1)*(2c+1), Dk = (2c+1)
  uint64_t Mj, Mk;        // magic multipliers: q = (n*M)>>47, exact for n<2^24
};

__device__ __forceinline__ int iabs_(int x) { return x < 0 ? -x : x; }

// Bit-exact replica of the reference's numpy fp64 nmax(): no fp contraction,
// same op order: cross -> ln=sqrt(dot) -> d=|dot(dr, cr/ln)| -> floor((co+d)/vol*ln)
__device__ __forceinline__ int nmax_ref(double u0, double u1, double u2,
                                        double v0, double v1, double v2,
                                        double dr0, double dr1, double dr2,
                                        double co, double vol) {
#pragma clang fp contract(off)
  double x0 = u1 * v2 - u2 * v1;
  double x1 = u2 * v0 - u0 * v2;
  double x2 = u0 * v1 - u1 * v0;
  double ln = sqrt((x0 * x0 + x1 * x1) + x2 * x2);
  double d  = fabs((dr0 * (x0 / ln) + dr1 * (x1 / ln)) + dr2 * (x2 / ln));
  double f  = floor((co + d) / vol * ln);
  long long n = (long long)f;
  if (n > 100000) n = 100000;
  return (int)n;
}

__global__ void setup_kernel(const float* __restrict__ cell,
                             const float* __restrict__ cutoff,
                             const float* __restrict__ r1,
                             const float* __restrict__ r2,
                             Params* __restrict__ p, int N) {
#pragma clang fp contract(off)
  double a0 = cell[0], a1 = cell[1], a2 = cell[2];
  double b0 = cell[3], b1 = cell[4], b2 = cell[5];
  double c0 = cell[6], c1 = cell[7], c2 = cell[8];
  double dr0 = (double)r2[0] - (double)r1[0];
  double dr1 = (double)r2[1] - (double)r1[1];
  double dr2 = (double)r2[2] - (double)r1[2];
  double co  = (double)cutoff[0];

  double bc0 = b1 * c2 - b2 * c1;
  double bc1 = b2 * c0 - b0 * c2;
  double bc2 = b0 * c1 - b1 * c0;
  double vol = fabs((a0 * bc0 + a1 * bc1) + a2 * bc2);

  int am = nmax_ref(b0, b1, b2, c0, c1, c2, dr0, dr1, dr2, co, vol);
  int bm = nmax_ref(a0, a1, a2, c0, c1, c2, dr0, dr1, dr2, co, vol);
  int cm = nmax_ref(a0, a1, a2, b0, b1, b2, dr0, dr1, dr2, co, vol);

  // Safety net: N = out_size/7 from the harness; if a 1-ulp divergence from
  // numpy shifted a bound, search +-1 perturbations for a product match.
  int fa = am, fb = bm, fc = cm;
  bool found = ((long long)(2 * am + 1) * (2 * bm + 1) * (2 * cm + 1) == (long long)N);
  for (int r = 1; r <= 3 && !found; ++r)
    for (int da = -1; da <= 1 && !found; ++da)
      for (int db = -1; db <= 1 && !found; ++db)
        for (int dc = -1; dc <= 1 && !found; ++dc) {
          if (iabs_(da) + iabs_(db) + iabs_(dc) != r) continue;
          long long A = am + da, B = bm + db, C = cm + dc;
          if (A < 0 || B < 0 || C < 0) continue;
          long long P = (2 * A + 1) * (2 * B + 1) * (2 * C + 1);
          if (P == (long long)N) { fa = (int)A; fb = (int)B; fc = (int)C; found = true; }
        }

  p->a_max = fa; p->b_max = fb; p->c_max = fc;
  uint32_t Dk = (uint32_t)(2 * fc + 1);
  uint32_t Dj = (uint32_t)(2 * fb + 1) * Dk;
  p->Dk = Dk; p->Dj = Dj;
  p->Mj = ((1ULL << 47) / Dj) + 1;
  p->Mk = ((1ULL << 47) / Dk) + 1;
}

// One block = 1024 consecutive lattice points (4/thread). Compute into LDS
// with each region pre-shifted by its global mod-16B phase, then copy out with
// 16B-aligned float4 stores (1 KB/wave-instr — the fillBuffer pattern that
// measures 6.7 TB/s on this chip) plus 1-3 dword head/tail peels.
__global__ __launch_bounds__(256) void periodic_main(
    const float* __restrict__ cell, const float* __restrict__ cutoff,
    const float* __restrict__ r1, const float* __restrict__ r2,
    const Params* __restrict__ p, float* __restrict__ out, int N) {
  __shared__ __align__(16) float s_vec[3 * 1024];          // region A, phase 0
  __shared__ __align__(16) float s_idx[4 + 3 * 1024];      // region B, phase s1
  __shared__ __align__(16) float s_msk[4 + 1024];          // region C, phase s2

  const int tid = threadIdx.x;
  const int n0  = blockIdx.x << 10;

  const int am = p->a_max, bm = p->b_max, cm = p->c_max;
  const uint32_t Dj = p->Dj, Dk = p->Dk;
  const uint64_t Mj = p->Mj, Mk = p->Mk;

  // wave-uniform scalar loads (L1-cached)
  const float ax = cell[0], ay = cell[1], az = cell[2];
  const float bx = cell[3], by = cell[4], bz = cell[5];
  const float cx = cell[6], cy = cell[7], cz = cell[8];
  const float drx = r2[0] - r1[0], dry = r2[1] - r1[1], drz = r2[2] - r1[2];
  const float co  = cutoff[0];
  const float co2 = co * co;

  // region base dword offsets and their mod-4 (dword) phases
  const size_t NN = (size_t)N;
  const size_t gA = (size_t)3 * (size_t)n0;
  const size_t gB = (size_t)3 * NN + (size_t)3 * (size_t)n0;
  const size_t gC = (size_t)6 * NN + (size_t)n0;
  const int s1 = (int)(gB & 3);   // n0 multiple of 1024 -> phase from 3N only
  const int s2 = (int)(gC & 3);

#pragma unroll
  for (int u = 0; u < 4; ++u) {
    const int pt = tid + (u << 8);
    const int n  = n0 + pt;
    if (n < N) {
      // magic-div decomposition n -> (i,j,k); exact for n < 2^24 (N ~ 8.1M)
      uint32_t un  = (uint32_t)n;
      uint32_t qi  = (uint32_t)(((uint64_t)un * Mj) >> 47);
      uint32_t rem = un - qi * Dj;
      uint32_t qj  = (uint32_t)(((uint64_t)rem * Mk) >> 47);
      uint32_t qk  = rem - qj * Dk;

      float fi = (float)((int)qi - am);
      float fj = (float)((int)qj - bm);
      float fk = (float)((int)qk - cm);

      // disp = ijk @ cell in f32, XLA-style k-ascending fmuladd accumulation
      float vx = fmaf(fk, cx, fmaf(fj, bx, fi * ax)) + drx;
      float vy = fmaf(fk, cy, fmaf(fj, by, fi * ay)) + dry;
      float vz = fmaf(fk, cz, fmaf(fj, bz, fi * az)) + drz;

      float s = fmaf(vz, vz, fmaf(vy, vy, vx * vx));
      bool  m = s < co2;

      int b3 = 3 * pt;
      s_vec[b3 + 0]      = m ? vx : 0.f;
      s_vec[b3 + 1]      = m ? vy : 0.f;
      s_vec[b3 + 2]      = m ? vz : 0.f;
      s_idx[s1 + b3 + 0] = m ? fi : 0.f;
      s_idx[s1 + b3 + 1] = m ? fj : 0.f;
      s_idx[s1 + b3 + 2] = m ? fk : 0.f;
      s_msk[s2 + pt]     = m ? 1.0f : 0.0f;
    }
  }
  __syncthreads();

  const int ptsLeft = N - n0;
  const int pts     = ptsLeft < 1024 ? ptsLeft : 1024;
  const int c3      = 3 * pts;

  // ---- region A (vectors): phase 0, pure float4 + tail ----
  {
    const int nf4 = c3 >> 2;
    const float4* src = reinterpret_cast<const float4*>(s_vec);
    float4* dst = reinterpret_cast<float4*>(out + gA);
    for (int i = tid; i < nf4; i += 256) dst[i] = src[i];
    const int tail = c3 & 3, tb = nf4 << 2;
    if (tid < tail) out[gA + tb + tid] = s_vec[tb + tid];
  }
  // ---- region B (indices): head to 16B phase, float4 middle, tail ----
  {
    int head = (4 - s1) & 3;
    if (head > c3) head = c3;
    if (tid < head) out[gB + tid] = s_idx[s1 + tid];
    const int rem = c3 - head;
    const int nf4 = rem >> 2;
    const float4* src = reinterpret_cast<const float4*>(&s_idx[s1 + head]); // s1+head==4 (or 0): aligned
    float4* dst = reinterpret_cast<float4*>(out + gB + head);
    for (int i = tid; i < nf4; i += 256) dst[i] = src[i];
    const int tail = rem & 3, tb = head + (nf4 << 2);
    if (tid < tail) out[gB + tb + tid] = s_idx[s1 + tb + tid];
  }
  // ---- region C (mask): head to 16B phase, float4 middle, tail ----
  {
    int head = (4 - s2) & 3;
    if (head > pts) head = pts;
    if (tid < head) out[gC + tid] = s_msk[s2 + tid];
    const int rem = pts - head;
    const int nf4 = rem >> 2;
    const float4* src = reinterpret_cast<const float4*>(&s_msk[s2 + head]);
    float4* dst = reinterpret_cast<float4*>(out + gC + head);
    for (int i = tid; i < nf4; i += 256) dst[i] = src[i];
    const int tail = rem & 3, tb = head + (nf4 << 2);
    if (tid < tail) out[gC + tb + tid] = s_msk[s2 + tb + tid];
  }
}

extern "C" void kernel_launch(void* const* d_in, const int* in_sizes, int n_in,
                              void* d_out, int out_size, void* d_ws, size_t ws_size,
                              hipStream_t stream) {
  const float* cell   = (const float*)d_in[0];
  const float* cutoff = (const float*)d_in[1];
  const float* r1     = (const float*)d_in[2];
  const float* r2     = (const float*)d_in[3];
  float* out = (float*)d_out;

  int N = out_size / 7;
  Params* p = (Params*)d_ws;

  setup_kernel<<<1, 1, 0, stream>>>(cell, cutoff, r1, r2, p, N);
  int blocks = (N + 1023) / 1024;
  periodic_main<<<blocks, 256, 0, stream>>>(cell, cutoff, r1, r2, p, out, N);
}